// Round 10
// baseline (949.763 us; speedup 1.0000x reference)
//
#include <hip/hip_runtime.h>
#include <math.h>

#define BB   16
#define NN   32768
#define GG   128
#define KK   64
#define EDD  384
#define NT1  1024
#define PPT  32   // NN / NT1 (topk phase)
#define SB   4    // fps blocks per batch
#define SP   (NN / SB)   // 8192 points per fps block
#define JP   (SP / NT1)  // 8 iters/thread
#define MAGIC 0x13572468u

// ---- workspace layout (float offsets) ----
#define WS_GC     0        // [16][2][3] = 96 (c0, cm per batch)
#define WS_FLAGCM 96       // u32[16] cm-ready flags
#define WS_SYNC   128      // u64 [128][16][4] = 16384 floats
#define WS_FLAG2  16512    // u32[32] f2/sfg-ready flags
#define WS_CNT    16544    // u32[32] helper arrival counters
#define WS_SFG    16576    // [32][512]
#define WS_F2     32960    // [32][256][64]
#define WS_TSUM   557248   // [32][384][64] token partial sums
// total 1,343,680 floats ~= 5.4 MB (<= proven 6.4 MB usage)

__device__ __forceinline__ float sq3(float a, float b, float c) {
  // matches np: ((a*a + b*b) + c*c), no FMA contraction
  return __fadd_rn(__fadd_rn(__fmul_rn(a, a), __fmul_rn(b, b)), __fmul_rn(c, c));
}
__device__ __forceinline__ float dot3(float ax, float ay, float az,
                                      float bx, float by, float bz) {
  return __fadd_rn(__fadd_rn(__fmul_rn(ax, bx), __fmul_rn(ay, by)), __fmul_rn(az, bz));
}
__device__ __forceinline__ unsigned long long shfl_xor_u64(unsigned long long v,
                                                           int off) {
  unsigned lo = (unsigned)v, hi = (unsigned)(v >> 32);
  lo = __shfl_xor(lo, off);
  hi = __shfl_xor(hi, off);
  return ((unsigned long long)hi << 32) | lo;
}

// LDS float offsets for fps role (pts4 = float4{x,y,z,dist}[SP])
#define OFF_RED  (4 * SP)              // u64[2][16] parity partials
#define OFF_CENT (4 * SP + 64)         // float[GG*3]
#define OFF_DARR (OFF_CENT + GG * 3)   // float[GG]
#define OFF_MSH  (OFF_DARR + GG)
#define ALL_LDS_FLOATS (NN + 1408)

// ---------------------------------------------------------------------------
// Single fused kernel, 224 blocks x 1024, three roles:
//   gb in [0,64):    FPS (4 blocks/batch, b = gb&15 -> all 4 on XCD b%8).
//   gb in [64,96):   group LEADER g=gb-64: topk + encA + sfg; writes f2/sfg
//                    to ws, zeros tsum/cnt, releases flag2[g].
//                    which=0 uses c0 (overlaps fps); which=1 spins on flagCM.
//   gb in [96,224):  HELPER h=gb-96, g=h>>2, pc=h&3: spins on flag2[g];
//                    encB rows [pc*128,+128) (8 rows/wave, lane=k, s_load
//                    weights) -> f4q LDS; encC partials (one running acc,
//                    no wide register arrays -> no spill) atomicAdd into
//                    tsum[g]; last arrival (acq_rel cnt) does max_k + b4 +
//                    broadcast to out.
// All 224 blocks co-resident (<=256 CUs, 1 block/CU at 133 KB LDS) -> spins
// deadlock-free. Harness re-poisons ws to 0xAA before every launch: flags
// start != MAGIC, fps slots start top-bit-set (invalid).
// R9 post-mortem applied: encB/encC parallelism restored to 128 blocks
// (R7-R9 ran them on 32 -> ~460 us tail); register arrays capped at 8.
// ---------------------------------------------------------------------------
__global__ void __launch_bounds__(NT1) k_all(
    const float* __restrict__ points, float* __restrict__ out,
    float* __restrict__ ws,
    const float* __restrict__ w1, const float* __restrict__ b1,
    const float* __restrict__ g1, const float* __restrict__ be1,
    const float* __restrict__ m1, const float* __restrict__ v1,
    const float* __restrict__ w2, const float* __restrict__ b2,
    const float* __restrict__ w3, const float* __restrict__ b3,
    const float* __restrict__ g2, const float* __restrict__ be2,
    const float* __restrict__ m2, const float* __restrict__ v2,
    const float* __restrict__ w4, const float* __restrict__ b4) {
  extern __shared__ float smem[];
  const int gb = blockIdx.x;
  const int t  = threadIdx.x;

  if (gb < 64) {
    // ================= FPS role (R5-R9 proven, unchanged) =================
    float4* pts = (float4*)smem;                                       // [SP]
    unsigned long long* redp = (unsigned long long*)(smem + OFF_RED);  // [2][16]
    float* cent = smem + OFF_CENT;   // [GG*3]
    float* darr = smem + OFF_DARR;   // [GG]
    int*   msh  = (int*)(smem + OFF_MSH);

    const int b = gb & 15, blk = gb >> 4;  // XCD-swizzled: gb%8 == b%8
    const float* P = points + (size_t)b * NN * 3;
    const int base = blk * SP;
    unsigned long long* slots = (unsigned long long*)(ws + WS_SYNC);

#pragma unroll
    for (int j = 0; j < JP; ++j) {
      int q = t + j * NT1;
      const float* pp = P + (size_t)(base + q) * 3;
      pts[q] = make_float4(pp[0], pp[1], pp[2], INFINITY);
    }
    float cx = P[0], cy = P[1], cz = P[2];  // centroid 0 = point 0
    if (blk == 0 && t == 0) { cent[0] = cx; cent[1] = cy; cent[2] = cz; }
    __syncthreads();

    for (int it = 1; it < GG; ++it) {
      unsigned long long bp = 0ULL;
#pragma unroll
      for (int j = 0; j < JP; ++j) {
        int q = t + j * NT1;
        float4 v = pts[q];
        float dx = __fsub_rn(v.x, cx);
        float dy = __fsub_rn(v.y, cy);
        float dz = __fsub_rn(v.z, cz);
        float d  = __fadd_rn(__fadd_rn(__fmul_rn(dx, dx), __fmul_rn(dy, dy)),
                             __fmul_rn(dz, dz));
        float nd = fminf(v.w, d);
        pts[q] = make_float4(v.x, v.y, v.z, nd);
        unsigned long long cand =
            ((unsigned long long)__float_as_uint(nd) << 32) |
            (unsigned)(~(base + q));
        if (cand > bp) bp = cand;
      }
#pragma unroll
      for (int off = 1; off < 64; off <<= 1) {
        unsigned long long o = shfl_xor_u64(bp, off);
        if (o > bp) bp = o;
      }
      const int par = (it & 1) * 16;
      if ((t & 63) == 0) redp[par + (t >> 6)] = bp;
      __syncthreads();  // the ONLY barrier per round (parity protects redp)
      unsigned long long v = redp[par + (t & 15)];
#pragma unroll
      for (int off = 1; off < 16; off <<= 1) {
        unsigned long long o = shfl_xor_u64(v, off);
        if (o > v) v = o;
      }
      if (t == 0)
        __hip_atomic_store(&slots[(size_t)it * 64 + b * 4 + blk], v,
                           __ATOMIC_RELAXED, __HIP_MEMORY_SCOPE_AGENT);
      unsigned long long o = 0ULL;
      if ((t & 63) < 4) {
        do {
          o = __hip_atomic_load(&slots[(size_t)it * 64 + b * 4 + (t & 3)],
                                __ATOMIC_RELAXED, __HIP_MEMORY_SCOPE_AGENT);
        } while ((long long)o < 0);  // poison/invalid: top bit set; d>=0 clear
      }
      {
        unsigned long long o1 = shfl_xor_u64(o, 1);
        if (o1 > o) o = o1;
        unsigned long long o2 = shfl_xor_u64(o, 2);
        if (o2 > o) o = o2;
      }
      int sv = ~__shfl((int)(unsigned)(o & 0xFFFFFFFFull), 0);
      const float* wp = P + (size_t)(unsigned)sv * 3;  // uniform -> broadcast
      cx = wp[0]; cy = wp[1]; cz = wp[2];
      if (blk == 0 && t == 0) {
        cent[it * 3 + 0] = cx; cent[it * 3 + 1] = cy; cent[it * 3 + 2] = cz;
      }
    }

    if (blk != 0) return;  // epilogue on block 0 of each batch only
    __syncthreads();

    if (t < GG) {  // morton m = argmin_{j>=1} cdist(c0,cj), ref formula
      float c0x = cent[0], c0y = cent[1], c0z = cent[2];
      float cjx = cent[t * 3 + 0], cjy = cent[t * 3 + 1], cjz = cent[t * 3 + 2];
      float sa = sq3(c0x, c0y, c0z);
      float sb = sq3(cjx, cjy, cjz);
      float dt = dot3(c0x, c0y, c0z, cjx, cjy, cjz);
      float dd = __fsub_rn(__fadd_rn(sa, sb), __fmul_rn(2.0f, dt));
      darr[t] = (t == 0) ? INFINITY : dd;
    }
    __syncthreads();
    if (t == 0) {
      float vd = darr[1]; int vi = 1;
      for (int j = 2; j < GG; ++j) {
        float od = darr[j];
        if (od < vd) { vd = od; vi = j; }  // strict < => first-min
      }
      msh[0] = vi;
      float* gc = ws + WS_GC + b * 6;
      gc[0] = cent[0];          gc[1] = cent[1];          gc[2] = cent[2];
      gc[3] = cent[vi * 3 + 0]; gc[4] = cent[vi * 3 + 1]; gc[5] = cent[vi * 3 + 2];
      __hip_atomic_store((unsigned*)(ws + WS_FLAGCM) + b, MAGIC,
                         __ATOMIC_RELEASE, __HIP_MEMORY_SCOPE_AGENT);
    }
    __syncthreads();
    int m = msh[0];
    if (t < GG * 3) {  // pos0=c0, pos1=cm, pos>=2=c0 (morton degeneracy)
      int pos = t / 3, c = t % 3;
      float v = (pos == 1) ? cent[m * 3 + c] : cent[c];
      out[(size_t)b * GG * 3 + t] = v;
    }
    return;
  }

  if (gb < 96) {
    // ==================== group LEADER role ====================
    float* darr = smem;                        // [NN] (topk phase)
    float* f1s  = smem;                        // [128*65] = 8320 (overlay)
    float* redd = smem + NN;                   // [2][16]
    int*   redi = (int*)(smem + NN + 32);      // [2][16]
    float* xl   = smem + NN + 64;              // [KK*3]
    float* fgs  = smem + NN + 256;             // [256]

    const int g = gb - 64;
    const int b = g >> 1, which = g & 1;
    const float* P = points + (size_t)b * NN * 3;
    float cx, cy, cz;
    if (which == 0) {
      cx = P[0]; cy = P[1]; cz = P[2];  // c0 known at t0 -> overlaps fps
    } else {
      unsigned* flagp = (unsigned*)(ws + WS_FLAGCM) + b;
      unsigned f;
      do {
        f = __hip_atomic_load(flagp, __ATOMIC_ACQUIRE, __HIP_MEMORY_SCOPE_AGENT);
        if (f != MAGIC) __builtin_amdgcn_s_sleep(16);
      } while (f != MAGIC);
      const float* gc = ws + WS_GC + b * 6 + 3;
      cx = gc[0]; cy = gc[1]; cz = gc[2];
    }
    const float sa = sq3(cx, cy, cz);

    // ---- phase 1: top-64 extraction (proven structure) ----
    float bd = INFINITY; int bg = 0;
#pragma unroll
    for (int j = 0; j < PPT; ++j) {
      int p = t + j * NT1;
      const float* pp = P + (size_t)p * 3;
      float px = pp[0], py = pp[1], pz = pp[2];
      float sb = sq3(px, py, pz);
      float dt = dot3(cx, cy, cz, px, py, pz);
      float d  = __fsub_rn(__fadd_rn(sa, sb), __fmul_rn(2.0f, dt));
      darr[p] = d;
      if (d < bd) { bd = d; bg = p; }  // ascending p + strict < => first-min
    }
    int my_win = 0;
    for (int r = 0; r < KK; ++r) {
      float rd = bd; int ri = bg;
#pragma unroll
      for (int off = 1; off < 64; off <<= 1) {
        float od = __shfl_xor(rd, off);
        int   oi = __shfl_xor(ri, off);
        if (od < rd || (od == rd && oi < ri)) { rd = od; ri = oi; }
      }
      const int par = (r & 1) * 16;
      if ((t & 63) == 0) { redd[par + (t >> 6)] = rd; redi[par + (t >> 6)] = ri; }
      __syncthreads();
      int l = t & 15;
      float vd = redd[par + l]; int vi = redi[par + l];
#pragma unroll
      for (int off = 1; off < 16; off <<= 1) {
        float od = __shfl_xor(vd, off);
        int   oi = __shfl_xor(vi, off);
        if (od < vd || (od == vd && oi < vi)) { vd = od; vi = oi; }
      }
      if (t == r) my_win = vi;
      if (t == (vi & (NT1 - 1))) {  // owner invalidates + rescans
        darr[vi] = INFINITY;
        bd = INFINITY; bg = 0;
#pragma unroll
        for (int j = 0; j < PPT; ++j) {
          int p = t + j * NT1;
          float v = darr[p];
          if (v < bd) { bd = v; bg = p; }
        }
      }
    }
    __syncthreads();  // darr dead after this point
    if (t < KK) {
      const float* pp = P + (size_t)my_win * 3;
      xl[t * 3 + 0] = __fsub_rn(pp[0], cx);
      xl[t * 3 + 1] = __fsub_rn(pp[1], cy);
      xl[t * 3 + 2] = __fsub_rn(pp[2], cz);
    }
    __syncthreads();

    // ---- phase 2: f1 = relu(bn1(w1@x + b1)) -> f1s[128][65] ----
    {
      const int o = t & 127, kh = t >> 7;  // kh in [0,8)
      float wx = w1[o * 3 + 0], wy = w1[o * 3 + 1], wz = w1[o * 3 + 2];
      float inv = g1[o] * (1.0f / sqrtf(v1[o] + 1e-5f));
      float add = be1[o] - m1[o] * inv;
      float bb = b1[o];
#pragma unroll
      for (int kk = 0; kk < 8; ++kk) {
        int k = kh * 8 + kk;
        float f = fmaf(wx, xl[k * 3 + 0],
                  fmaf(wy, xl[k * 3 + 1],
                  fmaf(wz, xl[k * 3 + 2], bb)));
        f = fmaf(f, inv, add);
        f1s[o * 65 + k] = fmaxf(f, 0.0f);
      }
    }
    __syncthreads();

    const int k  = t & 63;
    const int wg = __builtin_amdgcn_readfirstlane(t >> 6);  // [0,16) uniform

    // ---- phase 3: f2 = w2@f1 + b2 -> ws; fg = max_k -> fgs LDS ----
    float* f2g = ws + WS_F2 + (size_t)g * 256 * 64;
    {
      const int o0 = wg * 16;
      float acc[16];
#pragma unroll
      for (int oo = 0; oo < 16; ++oo) acc[oo] = b2[o0 + oo];
      for (int i = 0; i < 128; ++i) {
        float xv = f1s[i * 65 + k];
#pragma unroll
        for (int oo = 0; oo < 16; ++oo)
          acc[oo] = fmaf(w2[(o0 + oo) * 128 + i], xv, acc[oo]);  // s_load
      }
#pragma unroll
      for (int oo = 0; oo < 16; ++oo) f2g[(o0 + oo) * 64 + k] = acc[oo];
#pragma unroll
      for (int oo = 0; oo < 16; ++oo) {
        float v = acc[oo];
#pragma unroll
        for (int off = 1; off < 64; off <<= 1) v = fmaxf(v, __shfl_xor(v, off));
        if (k == 0) fgs[o0 + oo] = v;
      }
    }
    __syncthreads();

    // ---- phase 4: sfg[o] = b3[o] + sum_{i<256} w3[o][i]*fg[i] -> ws ----
    float* sfgg = ws + WS_SFG + (size_t)g * 512;
    for (int rr = 0; rr < 32; ++rr) {
      int o = wg * 32 + rr;
      const float* wr = w3 + (size_t)o * 512;
      float s = 0.0f;
#pragma unroll
      for (int c = 0; c < 4; ++c)
        s = fmaf(wr[c * 64 + k], fgs[c * 64 + k], s);
#pragma unroll
      for (int off = 1; off < 64; off <<= 1) s += __shfl_xor(s, off);
      if (k == 0) sfgg[o] = s + b3[o];
    }

    // ---- zero tsum[g] + cnt[g], then release flag2[g] ----
    float4* tz = (float4*)(ws + WS_TSUM + (size_t)g * EDD * 64);
    float4 z4 = make_float4(0.f, 0.f, 0.f, 0.f);
    for (int j = t; j < EDD * 64 / 4; j += NT1) tz[j] = z4;
    if (t == 0)
      __hip_atomic_store((unsigned*)(ws + WS_CNT) + g, 0u,
                         __ATOMIC_RELAXED, __HIP_MEMORY_SCOPE_AGENT);
    __syncthreads();  // all stores drained (vmcnt(0) before barrier)
    if (t == 0)
      __hip_atomic_store((unsigned*)(ws + WS_FLAG2) + g, MAGIC,
                         __ATOMIC_RELEASE, __HIP_MEMORY_SCOPE_AGENT);
    return;
  }

  // ==================== HELPER role ====================
  float* f2L  = smem;            // [256*64] = 16384
  float* f4q  = smem + 16384;    // [128*64] = 8192
  float* tokm = smem + 24576;    // [384]
  int*   oldp = (int*)(smem + 24960);

  const int h = gb - 96;
  const int g = h >> 2, pc = h & 3;
  const int b = g >> 1, which = g & 1;
  {
    unsigned* flagp = (unsigned*)(ws + WS_FLAG2) + g;
    unsigned f;
    do {
      f = __hip_atomic_load(flagp, __ATOMIC_ACQUIRE, __HIP_MEMORY_SCOPE_AGENT);
      if (f != MAGIC) __builtin_amdgcn_s_sleep(8);
    } while (f != MAGIC);
  }
  const float* f2g  = ws + WS_F2 + (size_t)g * 256 * 64;
  const float* sfgg = ws + WS_SFG + (size_t)g * 512;
  float* tsum = ws + WS_TSUM + (size_t)g * EDD * 64;

  // stage f2 into LDS (coalesced)
  for (int j = t; j < 256 * 64; j += NT1) f2L[j] = f2g[j];
  __syncthreads();

  const int k  = t & 63;
  const int wg = __builtin_amdgcn_readfirstlane(t >> 6);  // [0,16) uniform

  // ---- encB: rows o = pc*128 + wg*8 + r (8 rows/wave, weights s_load) ----
  {
    float a8[8];
#pragma unroll
    for (int r = 0; r < 8; ++r) a8[r] = sfgg[pc * 128 + wg * 8 + r];
#pragma unroll 4
    for (int i = 0; i < 256; ++i) {
      float xv = f2L[i * 64 + k];
#pragma unroll
      for (int r = 0; r < 8; ++r)
        a8[r] = fmaf(w3[(size_t)(pc * 128 + wg * 8 + r) * 512 + 256 + i],
                     xv, a8[r]);  // uniform row -> s_load
    }
#pragma unroll
    for (int r = 0; r < 8; ++r) {
      int o = pc * 128 + wg * 8 + r;
      float inv = g2[o] * (1.0f / sqrtf(v2[o] + 1e-5f));
      float add = be2[o] - m2[o] * inv;
      f4q[(wg * 8 + r) * 64 + k] = fmaxf(fmaf(a8[r], inv, add), 0.0f);
    }
  }
  __syncthreads();

  // ---- encC partial over this 128-row chunk: one running acc per o4 ----
  for (int cc = 0; cc < 24; ++cc) {
    const int o4 = wg * 24 + cc;
    const float* wr = w4 + (size_t)o4 * 512 + pc * 128;
    float s0 = 0.f, s1 = 0.f, s2 = 0.f, s3 = 0.f;
    for (int i = 0; i < 128; i += 4) {
      s0 = fmaf(wr[i + 0], f4q[(i + 0) * 64 + k], s0);
      s1 = fmaf(wr[i + 1], f4q[(i + 1) * 64 + k], s1);
      s2 = fmaf(wr[i + 2], f4q[(i + 2) * 64 + k], s2);
      s3 = fmaf(wr[i + 3], f4q[(i + 3) * 64 + k], s3);
    }
    atomicAdd(&tsum[o4 * 64 + k], (s0 + s1) + (s2 + s3));
  }
  __syncthreads();  // all atomics issued+drained before arrival

  if (t == 0) {
    int old = (int)__hip_atomic_fetch_add((unsigned*)(ws + WS_CNT) + g, 1u,
                                          __ATOMIC_ACQ_REL,
                                          __HIP_MEMORY_SCOPE_AGENT);
    *oldp = old;
  }
  __syncthreads();
  if (*oldp != 3) return;  // not last -> done

  // ---- last helper: token[o4] = b4[o4] + max_k tsum; broadcast to out ----
  for (int cc = 0; cc < 24; ++cc) {
    const int o4 = wg * 24 + cc;
    float v = tsum[o4 * 64 + k];
#pragma unroll
    for (int off = 1; off < 64; off <<= 1) v = fmaxf(v, __shfl_xor(v, off));
    if (k == 0) tokm[o4] = v + b4[o4];
  }
  __syncthreads();
  float* tok = out + (size_t)BB * GG * 3;
  if (which == 1) {
    if (t < EDD) tok[((size_t)b * GG + 1) * EDD + t] = tokm[t];
  } else {
    for (int idx = t; idx < GG * EDD; idx += NT1) {
      int pos = idx / EDD, o = idx - pos * EDD;
      if (pos != 1) tok[((size_t)b * GG + pos) * EDD + o] = tokm[o];
    }
  }
}

extern "C" void kernel_launch(void* const* d_in, const int* in_sizes, int n_in,
                              void* d_out, int out_size, void* d_ws, size_t ws_size,
                              hipStream_t stream) {
  const float* points = (const float*)d_in[0];
  const float* w1  = (const float*)d_in[1];
  const float* b1  = (const float*)d_in[2];
  const float* g1  = (const float*)d_in[3];
  const float* be1 = (const float*)d_in[4];
  const float* m1  = (const float*)d_in[5];
  const float* v1  = (const float*)d_in[6];
  const float* w2  = (const float*)d_in[7];
  const float* b2  = (const float*)d_in[8];
  const float* w3  = (const float*)d_in[9];
  const float* b3  = (const float*)d_in[10];
  const float* g2  = (const float*)d_in[11];
  const float* be2 = (const float*)d_in[12];
  const float* m2  = (const float*)d_in[13];
  const float* v2  = (const float*)d_in[14];
  const float* w4  = (const float*)d_in[15];
  const float* b4  = (const float*)d_in[16];
  float* out = (float*)d_out;
  float* ws  = (float*)d_ws;

  size_t dyn = (size_t)ALL_LDS_FLOATS * sizeof(float);
  hipFuncSetAttribute(reinterpret_cast<const void*>(k_all),
                      hipFuncAttributeMaxDynamicSharedMemorySize, (int)dyn);

  // No memset: harness poisons d_ws to 0xAA before every launch (flags !=
  // MAGIC, fps slots top-bit-set = invalid); tsum/cnt are zeroed in-kernel
  // by the group leader before flag2 release.
  hipLaunchKernelGGL(k_all, dim3(64 + 32 + 128), dim3(NT1), dyn, stream,
                     points, out, ws, w1, b1, g1, be1, m1, v1, w2, b2,
                     w3, b3, g2, be2, m2, v2, w4, b4);
}

// Round 11
// 631.085 us; speedup vs baseline: 1.5050x; 1.5050x over previous
//
#include <hip/hip_runtime.h>
#include <math.h>

#define BB   16
#define NN   32768
#define GG   128
#define KK   64
#define EDD  384
#define NT1  1024
#define PPT  32   // NN / NT1 (topk phase)
#define SB   4    // fps blocks per batch
#define SP   (NN / SB)   // 8192 points per fps block
#define JP   (SP / NT1)  // 8 iters/thread
#define MAGIC 0x13572468u

// ---- workspace layout (float offsets) ----
#define WS_GC     0        // [16][2][3] = 96 (c0, cm per batch)
#define WS_FLAGCM 96       // u32[16] cm-ready flags
#define WS_SYNC   128      // u64 [128][16][4] = 16384 floats
#define WS_FG     16512    // [32][256]
#define WS_F2     24704    // [32][256][64]
#define WS_F4     548992   // [32][512][64]
// total 1,597,568 floats ~= 6.4 MB

__device__ __forceinline__ float sq3(float a, float b, float c) {
  // matches np: ((a*a + b*b) + c*c), no FMA contraction
  return __fadd_rn(__fadd_rn(__fmul_rn(a, a), __fmul_rn(b, b)), __fmul_rn(c, c));
}
__device__ __forceinline__ float dot3(float ax, float ay, float az,
                                      float bx, float by, float bz) {
  return __fadd_rn(__fadd_rn(__fmul_rn(ax, bx), __fmul_rn(ay, by)), __fmul_rn(az, bz));
}
__device__ __forceinline__ unsigned long long shfl_xor_u64(unsigned long long v,
                                                           int off) {
  unsigned lo = (unsigned)v, hi = (unsigned)(v >> 32);
  lo = __shfl_xor(lo, off);
  hi = __shfl_xor(hi, off);
  return ((unsigned long long)hi << 32) | lo;
}

// LDS float offsets for fps role (pts4 = float4{x,y,z,dist}[SP])
#define OFF_RED  (4 * SP)              // u64[2][16] parity partials
#define OFF_CENT (4 * SP + 64)         // float[GG*3]
#define OFF_DARR (OFF_CENT + GG * 3)   // float[GG]
#define OFF_MSH  (OFF_DARR + GG)
#define ALL_LDS_FLOATS (NN + 1408)

// ---------------------------------------------------------------------------
// Dispatch 1: FPS (64 blocks) + group leaders (32 blocks), 96 x 1024.
//   FPS role: R5-R10 proven structure, untouched (337 us).
//   LEADER g: topk + encA; writes f2 -> WS_F2, fg -> WS_FG (R6 interface).
//     which=0 uses c0 = points[b,0] -> fully overlaps FPS.
//     which=1 waits for cm. R10 post-mortem fix: ONLY lane 0 spins, with
//     RELAXED loads + s_sleep(32); one acquire fence on exit + barrier.
//     (R9/R10 had 16k-130k threads doing agent-ACQUIRE loads per spin tick —
//     per-tick cache maintenance on the same cross-XCD fabric as FPS's
//     latency-critical slot loop; suspected cause of the 460+ us tails.)
// ---------------------------------------------------------------------------
__global__ void __launch_bounds__(NT1) k_fps_grp(
    const float* __restrict__ points, float* __restrict__ out,
    float* __restrict__ ws,
    const float* __restrict__ w1, const float* __restrict__ b1,
    const float* __restrict__ g1, const float* __restrict__ be1,
    const float* __restrict__ m1, const float* __restrict__ v1,
    const float* __restrict__ w2, const float* __restrict__ b2) {
  extern __shared__ float smem[];
  const int gb = blockIdx.x;
  const int t  = threadIdx.x;

  if (gb < 64) {
    // ================= FPS role (proven, unchanged) =================
    float4* pts = (float4*)smem;                                       // [SP]
    unsigned long long* redp = (unsigned long long*)(smem + OFF_RED);  // [2][16]
    float* cent = smem + OFF_CENT;   // [GG*3]
    float* darr = smem + OFF_DARR;   // [GG]
    int*   msh  = (int*)(smem + OFF_MSH);

    const int b = gb & 15, blk = gb >> 4;  // XCD-swizzled: gb%8 == b%8
    const float* P = points + (size_t)b * NN * 3;
    const int base = blk * SP;
    unsigned long long* slots = (unsigned long long*)(ws + WS_SYNC);

#pragma unroll
    for (int j = 0; j < JP; ++j) {
      int q = t + j * NT1;
      const float* pp = P + (size_t)(base + q) * 3;
      pts[q] = make_float4(pp[0], pp[1], pp[2], INFINITY);
    }
    float cx = P[0], cy = P[1], cz = P[2];  // centroid 0 = point 0
    if (blk == 0 && t == 0) { cent[0] = cx; cent[1] = cy; cent[2] = cz; }
    __syncthreads();

    for (int it = 1; it < GG; ++it) {
      unsigned long long bp = 0ULL;
#pragma unroll
      for (int j = 0; j < JP; ++j) {
        int q = t + j * NT1;
        float4 v = pts[q];
        float dx = __fsub_rn(v.x, cx);
        float dy = __fsub_rn(v.y, cy);
        float dz = __fsub_rn(v.z, cz);
        float d  = __fadd_rn(__fadd_rn(__fmul_rn(dx, dx), __fmul_rn(dy, dy)),
                             __fmul_rn(dz, dz));
        float nd = fminf(v.w, d);
        pts[q] = make_float4(v.x, v.y, v.z, nd);
        unsigned long long cand =
            ((unsigned long long)__float_as_uint(nd) << 32) |
            (unsigned)(~(base + q));
        if (cand > bp) bp = cand;
      }
#pragma unroll
      for (int off = 1; off < 64; off <<= 1) {
        unsigned long long o = shfl_xor_u64(bp, off);
        if (o > bp) bp = o;
      }
      const int par = (it & 1) * 16;
      if ((t & 63) == 0) redp[par + (t >> 6)] = bp;
      __syncthreads();  // the ONLY barrier per round (parity protects redp)
      unsigned long long v = redp[par + (t & 15)];
#pragma unroll
      for (int off = 1; off < 16; off <<= 1) {
        unsigned long long o = shfl_xor_u64(v, off);
        if (o > v) v = o;
      }
      if (t == 0)
        __hip_atomic_store(&slots[(size_t)it * 64 + b * 4 + blk], v,
                           __ATOMIC_RELAXED, __HIP_MEMORY_SCOPE_AGENT);
      unsigned long long o = 0ULL;
      if ((t & 63) < 4) {
        do {
          o = __hip_atomic_load(&slots[(size_t)it * 64 + b * 4 + (t & 3)],
                                __ATOMIC_RELAXED, __HIP_MEMORY_SCOPE_AGENT);
        } while ((long long)o < 0);  // poison/invalid: top bit set; d>=0 clear
      }
      {
        unsigned long long o1 = shfl_xor_u64(o, 1);
        if (o1 > o) o = o1;
        unsigned long long o2 = shfl_xor_u64(o, 2);
        if (o2 > o) o = o2;
      }
      int sv = ~__shfl((int)(unsigned)(o & 0xFFFFFFFFull), 0);
      const float* wp = P + (size_t)(unsigned)sv * 3;  // uniform -> broadcast
      cx = wp[0]; cy = wp[1]; cz = wp[2];
      if (blk == 0 && t == 0) {
        cent[it * 3 + 0] = cx; cent[it * 3 + 1] = cy; cent[it * 3 + 2] = cz;
      }
    }

    if (blk != 0) return;  // epilogue on block 0 of each batch only
    __syncthreads();

    if (t < GG) {  // morton m = argmin_{j>=1} cdist(c0,cj), ref formula
      float c0x = cent[0], c0y = cent[1], c0z = cent[2];
      float cjx = cent[t * 3 + 0], cjy = cent[t * 3 + 1], cjz = cent[t * 3 + 2];
      float sa = sq3(c0x, c0y, c0z);
      float sb = sq3(cjx, cjy, cjz);
      float dt = dot3(c0x, c0y, c0z, cjx, cjy, cjz);
      float dd = __fsub_rn(__fadd_rn(sa, sb), __fmul_rn(2.0f, dt));
      darr[t] = (t == 0) ? INFINITY : dd;
    }
    __syncthreads();
    if (t == 0) {
      float vd = darr[1]; int vi = 1;
      for (int j = 2; j < GG; ++j) {
        float od = darr[j];
        if (od < vd) { vd = od; vi = j; }  // strict < => first-min
      }
      msh[0] = vi;
      float* gc = ws + WS_GC + b * 6;
      gc[0] = cent[0];          gc[1] = cent[1];          gc[2] = cent[2];
      gc[3] = cent[vi * 3 + 0]; gc[4] = cent[vi * 3 + 1]; gc[5] = cent[vi * 3 + 2];
      __hip_atomic_store((unsigned*)(ws + WS_FLAGCM) + b, MAGIC,
                         __ATOMIC_RELEASE, __HIP_MEMORY_SCOPE_AGENT);
    }
    __syncthreads();
    int m = msh[0];
    if (t < GG * 3) {  // pos0=c0, pos1=cm, pos>=2=c0 (morton degeneracy)
      int pos = t / 3, c = t % 3;
      float v = (pos == 1) ? cent[m * 3 + c] : cent[c];
      out[(size_t)b * GG * 3 + t] = v;
    }
    return;
  }

  // ==================== group LEADER role (R6 k_grp body) ====================
  float* darr = smem;                        // [NN] (topk phase)
  float* f1s  = smem;                        // [128*65] = 8320 (overlay)
  float* redd = smem + NN;                   // [2][16]
  int*   redi = (int*)(smem + NN + 32);      // [2][16]
  float* xl   = smem + NN + 64;              // [KK*3]

  const int g = gb - 64;
  const int b = g >> 1, which = g & 1;
  const float* P = points + (size_t)b * NN * 3;
  if (which == 1) {
    if (t == 0) {  // single-lane RELAXED spin; fence once on exit
      unsigned f;
      do {
        f = __hip_atomic_load((unsigned*)(ws + WS_FLAGCM) + b,
                              __ATOMIC_RELAXED, __HIP_MEMORY_SCOPE_AGENT);
        if (f != MAGIC) __builtin_amdgcn_s_sleep(32);
      } while (f != MAGIC);
      __builtin_amdgcn_fence(__ATOMIC_ACQUIRE, "agent");
    }
    __syncthreads();  // releases block; L1 (and stale L2 lines) invalidated
  }
  float cx, cy, cz;
  if (which == 0) {
    cx = P[0]; cy = P[1]; cz = P[2];  // c0 known at t0 -> overlaps fps
  } else {
    const float* gc = ws + WS_GC + b * 6 + 3;
    cx = gc[0]; cy = gc[1]; cz = gc[2];
  }
  const float sa = sq3(cx, cy, cz);

  // ---- phase 1: top-64 extraction (proven structure) ----
  float bd = INFINITY; int bg = 0;
#pragma unroll
  for (int j = 0; j < PPT; ++j) {
    int p = t + j * NT1;
    const float* pp = P + (size_t)p * 3;
    float px = pp[0], py = pp[1], pz = pp[2];
    float sb = sq3(px, py, pz);
    float dt = dot3(cx, cy, cz, px, py, pz);
    float d  = __fsub_rn(__fadd_rn(sa, sb), __fmul_rn(2.0f, dt));
    darr[p] = d;
    if (d < bd) { bd = d; bg = p; }  // ascending p + strict < => first-min
  }
  int my_win = 0;
  for (int r = 0; r < KK; ++r) {
    float rd = bd; int ri = bg;
#pragma unroll
    for (int off = 1; off < 64; off <<= 1) {
      float od = __shfl_xor(rd, off);
      int   oi = __shfl_xor(ri, off);
      if (od < rd || (od == rd && oi < ri)) { rd = od; ri = oi; }
    }
    const int par = (r & 1) * 16;
    if ((t & 63) == 0) { redd[par + (t >> 6)] = rd; redi[par + (t >> 6)] = ri; }
    __syncthreads();
    int l = t & 15;
    float vd = redd[par + l]; int vi = redi[par + l];
#pragma unroll
    for (int off = 1; off < 16; off <<= 1) {
      float od = __shfl_xor(vd, off);
      int   oi = __shfl_xor(vi, off);
      if (od < vd || (od == vd && oi < vi)) { vd = od; vi = oi; }
    }
    if (t == r) my_win = vi;
    if (t == (vi & (NT1 - 1))) {  // owner invalidates + rescans its 32 slots
      darr[vi] = INFINITY;
      bd = INFINITY; bg = 0;
#pragma unroll
      for (int j = 0; j < PPT; ++j) {
        int p = t + j * NT1;
        float v = darr[p];
        if (v < bd) { bd = v; bg = p; }
      }
    }
  }
  __syncthreads();  // darr dead after this point
  if (t < KK) {
    const float* pp = P + (size_t)my_win * 3;
    xl[t * 3 + 0] = __fsub_rn(pp[0], cx);
    xl[t * 3 + 1] = __fsub_rn(pp[1], cy);
    xl[t * 3 + 2] = __fsub_rn(pp[2], cz);
  }
  __syncthreads();

  // ---- phase 2: f1 = relu(bn1(w1@x + b1)) -> f1s[128][65] ----
  {
    const int o = t & 127, kh = t >> 7;  // kh in [0,8)
    float wx = w1[o * 3 + 0], wy = w1[o * 3 + 1], wz = w1[o * 3 + 2];
    float inv = g1[o] * (1.0f / sqrtf(v1[o] + 1e-5f));
    float add = be1[o] - m1[o] * inv;
    float bb = b1[o];
#pragma unroll
    for (int kk = 0; kk < 8; ++kk) {
      int k = kh * 8 + kk;
      float f = fmaf(wx, xl[k * 3 + 0],
                fmaf(wy, xl[k * 3 + 1],
                fmaf(wz, xl[k * 3 + 2], bb)));
      f = fmaf(f, inv, add);
      f1s[o * 65 + k] = fmaxf(f, 0.0f);
    }
  }
  __syncthreads();

  // ---- phase 3: f2 = w2@f1 + b2 -> WS_F2; fg = max_k -> WS_FG ----
  {
    const int k  = t & 63;
    const int og = __builtin_amdgcn_readfirstlane(t >> 6);  // [0,16) uniform
    const int o0 = og * 16;
    float acc[16];
#pragma unroll
    for (int oo = 0; oo < 16; ++oo) acc[oo] = b2[o0 + oo];
    for (int i = 0; i < 128; ++i) {
      float xv = f1s[i * 65 + k];
#pragma unroll
      for (int oo = 0; oo < 16; ++oo)
        acc[oo] = fmaf(w2[(o0 + oo) * 128 + i], xv, acc[oo]);  // s_load
    }
    float* f2g = ws + WS_F2 + (size_t)g * 256 * 64;
    float* fgg = ws + WS_FG + g * 256;
#pragma unroll
    for (int oo = 0; oo < 16; ++oo) f2g[(o0 + oo) * 64 + k] = acc[oo];
#pragma unroll
    for (int oo = 0; oo < 16; ++oo) {
      float v = acc[oo];
#pragma unroll
      for (int off = 1; off < 64; off <<= 1) v = fmaxf(v, __shfl_xor(v, off));
      if (k == 0) fgg[o0 + oo] = v;
    }
  }
}

// ---------------------------------------------------------------------------
// Dispatch 2 (R6 k_encB verbatim): f4 = relu(bn2(w3@concat([fg,f2]) + b3))
// grid = 32 groups x 8 o-chunks of 64, 256 threads.
// ---------------------------------------------------------------------------
__global__ void __launch_bounds__(256) k_encB(
    float* __restrict__ ws,
    const float* __restrict__ w3, const float* __restrict__ b3,
    const float* __restrict__ g2, const float* __restrict__ be2,
    const float* __restrict__ m2, const float* __restrict__ v2) {
  __shared__ float part[4][64];
  __shared__ float sfg[64];
  const int blk = blockIdx.x;
  const int g = blk >> 3, oc = blk & 7;
  const int t = threadIdx.x;
  const int k = t & 63;
  const int og = __builtin_amdgcn_readfirstlane(t >> 6);
  const int ob = oc * 64;
  const float* fgg = ws + WS_FG + g * 256;
  {  // k-independent part: sum_{i<256} w3[o][i] * fg[i]
    int o = ob + k;
    float s = 0.0f;
    int i0 = og * 64;
    for (int ii = 0; ii < 64; ++ii) {
      int i = i0 + ii;
      s = fmaf(w3[(size_t)o * 512 + i], fgg[i], s);
    }
    part[og][k] = s;
  }
  __syncthreads();
  if (t < 64)
    sfg[t] = b3[ob + t] + ((part[0][t] + part[1][t]) + (part[2][t] + part[3][t]));
  __syncthreads();
  const int o0 = ob + og * 16;
  float acc[16];
#pragma unroll
  for (int oo = 0; oo < 16; ++oo) acc[oo] = sfg[og * 16 + oo];
  const float* f2g = ws + WS_F2 + (size_t)g * 256 * 64;
#pragma unroll 4
  for (int i = 0; i < 256; ++i) {
    float xv = f2g[i * 64 + k];
#pragma unroll
    for (int oo = 0; oo < 16; ++oo)
      acc[oo] = fmaf(w3[(size_t)(o0 + oo) * 512 + 256 + i], xv, acc[oo]);
  }
  float* f4g = ws + WS_F4 + (size_t)g * 512 * 64;
#pragma unroll
  for (int oo = 0; oo < 16; ++oo) {
    int o = o0 + oo;
    float inv = g2[o] * (1.0f / sqrtf(v2[o] + 1e-5f));
    float add = be2[o] - m2[o] * inv;
    f4g[o * 64 + k] = fmaxf(fmaf(acc[oo], inv, add), 0.0f);
  }
}

// ---------------------------------------------------------------------------
// Dispatch 3 (R6 k_encCb verbatim): token = max_k (w4@f4 + b4) broadcast to
// all output positions. grid = 32 x 12 chunks of 32, 256 threads.
// ---------------------------------------------------------------------------
__global__ void __launch_bounds__(256) k_encCb(float* __restrict__ ws,
                                               const float* __restrict__ w4,
                                               const float* __restrict__ b4,
                                               float* __restrict__ out) {
  const int blk = blockIdx.x;
  const int g = blk / 12, oc = blk % 12;
  const int b = g >> 1, which = g & 1;
  const int t = threadIdx.x;
  const int k = t & 63;
  const int og = __builtin_amdgcn_readfirstlane(t >> 6);
  const int o0 = oc * 32 + og * 8;
  float acc[8];
#pragma unroll
  for (int oo = 0; oo < 8; ++oo) acc[oo] = b4[o0 + oo];
  const float* f4g = ws + WS_F4 + (size_t)g * 512 * 64;
#pragma unroll 8
  for (int i = 0; i < 512; ++i) {
    float xv = f4g[i * 64 + k];
#pragma unroll
    for (int oo = 0; oo < 8; ++oo)
      acc[oo] = fmaf(w4[(size_t)(o0 + oo) * 512 + i], xv, acc[oo]);
  }
#pragma unroll
  for (int oo = 0; oo < 8; ++oo) {
#pragma unroll
    for (int off = 1; off < 64; off <<= 1)
      acc[oo] = fmaxf(acc[oo], __shfl_xor(acc[oo], off));
  }
  // all lanes hold the per-oo max; scatter to output positions
  float* tok = out + (size_t)BB * GG * 3;
  if (which == 1) {
    if (k == 0) {
      float* dst = tok + ((size_t)b * GG + 1) * EDD + o0;
#pragma unroll
      for (int oo = 0; oo < 8; ++oo) dst[oo] = acc[oo];
    }
  } else {
#pragma unroll
    for (int rep = 0; rep < 2; ++rep) {
      int pos = k + rep * 64;
      if (pos == 1) continue;
      float* dst = tok + ((size_t)b * GG + pos) * EDD + o0;
#pragma unroll
      for (int oo = 0; oo < 8; ++oo) dst[oo] = acc[oo];
    }
  }
}

extern "C" void kernel_launch(void* const* d_in, const int* in_sizes, int n_in,
                              void* d_out, int out_size, void* d_ws, size_t ws_size,
                              hipStream_t stream) {
  const float* points = (const float*)d_in[0];
  const float* w1  = (const float*)d_in[1];
  const float* b1  = (const float*)d_in[2];
  const float* g1  = (const float*)d_in[3];
  const float* be1 = (const float*)d_in[4];
  const float* m1  = (const float*)d_in[5];
  const float* v1  = (const float*)d_in[6];
  const float* w2  = (const float*)d_in[7];
  const float* b2  = (const float*)d_in[8];
  const float* w3  = (const float*)d_in[9];
  const float* b3  = (const float*)d_in[10];
  const float* g2  = (const float*)d_in[11];
  const float* be2 = (const float*)d_in[12];
  const float* m2  = (const float*)d_in[13];
  const float* v2  = (const float*)d_in[14];
  const float* w4  = (const float*)d_in[15];
  const float* b4  = (const float*)d_in[16];
  float* out = (float*)d_out;
  float* ws  = (float*)d_ws;

  size_t dyn = (size_t)ALL_LDS_FLOATS * sizeof(float);
  hipFuncSetAttribute(reinterpret_cast<const void*>(k_fps_grp),
                      hipFuncAttributeMaxDynamicSharedMemorySize, (int)dyn);

  // No memset: harness poisons d_ws to 0xAA before every launch (flagCM !=
  // MAGIC, fps slots top-bit-set = invalid); stale values also safe
  // (deterministic computation).
  hipLaunchKernelGGL(k_fps_grp, dim3(96), dim3(NT1), dyn, stream,
                     points, out, ws, w1, b1, g1, be1, m1, v1, w2, b2);
  hipLaunchKernelGGL(k_encB, dim3(256), dim3(256), 0, stream,
                     ws, w3, b3, g2, be2, m2, v2);
  hipLaunchKernelGGL(k_encCb, dim3(384), dim3(256), 0, stream, ws, w4, b4, out);
}